// Round 3
// baseline (1426.173 us; speedup 1.0000x reference)
//
#include <hip/hip_runtime.h>

#define NN 100000
#define NGRAPH 64
#define AVGLOG 3.4965075614664802f

using f32x4 = __attribute__((ext_vector_type(4))) float;
using s16x8 = __attribute__((ext_vector_type(8))) short;
using f16x8 = __attribute__((ext_vector_type(8))) _Float16;

// ---------------- CSR build ----------------
__global__ void k_degree(const int* __restrict__ ei, int* __restrict__ cnt, int E) {
  int e = blockIdx.x * 256 + threadIdx.x;
  if (e < E) atomicAdd(&cnt[ei[E + e]], 1);
}

__global__ void k_blocksum(const int* __restrict__ cnt, int* __restrict__ bsum, int n) {
  __shared__ int s[256];
  int i = blockIdx.x * 256 + threadIdx.x;
  s[threadIdx.x] = (i < n) ? cnt[i] : 0;
  __syncthreads();
  for (int off = 128; off > 0; off >>= 1) {
    if (threadIdx.x < off) s[threadIdx.x] += s[threadIdx.x + off];
    __syncthreads();
  }
  if (threadIdx.x == 0) bsum[blockIdx.x] = s[0];
}

__global__ void k_scanb(const int* __restrict__ bsum, int* __restrict__ boff, int nb) {
  __shared__ int s[512];
  int t = threadIdx.x;
  int v = (t < nb) ? bsum[t] : 0;
  s[t] = v;
  __syncthreads();
  for (int off = 1; off < 512; off <<= 1) {
    int u = (t >= off) ? s[t - off] : 0;
    __syncthreads();
    s[t] += u;
    __syncthreads();
  }
  if (t < nb) boff[t] = s[t] - v;  // exclusive block offsets
}

__global__ void k_scatter(const int* __restrict__ cnt, const int* __restrict__ boff,
                          int* __restrict__ row_ptr, int n, int etot) {
  __shared__ int s[256];
  int i = blockIdx.x * 256 + threadIdx.x;
  int v = (i < n) ? cnt[i] : 0;
  s[threadIdx.x] = v;
  __syncthreads();
  for (int off = 1; off < 256; off <<= 1) {
    int u = (threadIdx.x >= off) ? s[threadIdx.x - off] : 0;
    __syncthreads();
    s[threadIdx.x] += u;
    __syncthreads();
  }
  if (i < n) row_ptr[i] = boff[blockIdx.x] + s[threadIdx.x] - v;
  if (i == 0) row_ptr[n] = etot;
}

__global__ void k_nodesc(const int* __restrict__ cnt, const int* __restrict__ row_ptr,
                         int* __restrict__ cursor, float* __restrict__ invd,
                         float* __restrict__ s1v, float* __restrict__ s2v, int n) {
  int i = blockIdx.x * 256 + threadIdx.x;
  if (i >= n) return;
  cursor[i] = row_ptr[i];
  float degc = fmaxf((float)cnt[i], 1.f);
  invd[i] = 1.f / degc;
  float ld = logf(degc + 1.f);
  s1v[i] = ld * (1.f / AVGLOG);
  s2v[i] = AVGLOG / ld;
}

__global__ void k_fill(const int* __restrict__ ei, int* __restrict__ cursor,
                       int* __restrict__ colv, int E) {
  int e = blockIdx.x * 256 + threadIdx.x;
  if (e >= E) return;
  int pos = atomicAdd(&cursor[ei[E + e]], 1);
  colv[pos] = ei[e];
}

// W [K][FO] fp32 -> Wt [FOP][K] fp16 (rows >= FO zero-padded)
__global__ void k_wtprep(const float* __restrict__ W, _Float16* __restrict__ Wt,
                         int K, int FO, int FOP) {
  int i = blockIdx.x * 256 + threadIdx.x;
  if (i >= FOP * K) return;
  int nn = i / K, k = i - nn * K;
  float v = (nn < FO) ? W[k * FO + nn] : 0.f;
  Wt[i] = (_Float16)v;
}

// ---------------- fused PNA layer: aggregate + 13F GEMM (fp16 MFMA) ----------------
#define MFMA16(a, b, c) __builtin_amdgcn_mfma_f32_16x16x32_f16(a, b, c, 0, 0, 0)

template <int F, int FO, int FOP, bool RELU>
__launch_bounds__(256)
__global__ void k_pna(const float* __restrict__ hin, const int* __restrict__ row_ptr,
                      const int* __restrict__ colv, const float* __restrict__ invd,
                      const float* __restrict__ s1g, const float* __restrict__ s2g,
                      const _Float16* __restrict__ Wt, const float* __restrict__ bias,
                      float* __restrict__ hout) {
  constexpr int K13 = 13 * F;
  constexpr int AGW = 4 * F + 8;   // padded (stride % 32 dwords == 4 -> 2-way max)
  constexpr int XW = F + 8;
  constexpr int NT = FOP / 16;
  constexpr int PPW = (2 * NT) / 4;  // tile-pairs per wave: 3 / 2 / 1 / 1
  __shared__ __align__(16) _Float16 s_agg[32][AGW];
  __shared__ __align__(16) _Float16 s_x[32][XW];
  __shared__ __align__(16) _Float16 s_wt[3][FOP][40];

  const int tid = threadIdx.x;
  const int n0 = blockIdx.x * 32;

  // ---- Phase A: aggregation (8 threads per node, fp32 accum) ----
  {
    const int r = tid >> 3, g = tid & 7;
    const int n = n0 + r;
    const int e0 = row_ptr[n], e1 = row_ptr[n + 1];
    constexpr int J = F / 32;
    float sm[4 * J], sq[4 * J], mn[4 * J], mx[4 * J];
    const float FINF = __builtin_inff();
#pragma unroll
    for (int j = 0; j < 4 * J; ++j) { sm[j] = 0.f; sq[j] = 0.f; mn[j] = FINF; mx[j] = -FINF; }
    int e = e0;
    for (; e + 1 < e1; e += 2) {
      int sA = colv[e], sB = colv[e + 1];
      const float4* ra = (const float4*)(hin + (size_t)sA * F);
      const float4* rb = (const float4*)(hin + (size_t)sB * F);
#pragma unroll
      for (int j = 0; j < J; ++j) {
        float4 va = ra[g + 8 * j];
        float4 vb = rb[g + 8 * j];
        float av[4] = {va.x, va.y, va.z, va.w};
        float bv[4] = {vb.x, vb.y, vb.z, vb.w};
#pragma unroll
        for (int l = 0; l < 4; ++l) {
          sm[4 * j + l] += av[l] + bv[l];
          sq[4 * j + l] += av[l] * av[l] + bv[l] * bv[l];
          mn[4 * j + l] = fminf(mn[4 * j + l], fminf(av[l], bv[l]));
          mx[4 * j + l] = fmaxf(mx[4 * j + l], fmaxf(av[l], bv[l]));
        }
      }
    }
    if (e < e1) {
      int sA = colv[e];
      const float4* ra = (const float4*)(hin + (size_t)sA * F);
#pragma unroll
      for (int j = 0; j < J; ++j) {
        float4 va = ra[g + 8 * j];
        float av[4] = {va.x, va.y, va.z, va.w};
#pragma unroll
        for (int l = 0; l < 4; ++l) {
          sm[4 * j + l] += av[l];
          sq[4 * j + l] += av[l] * av[l];
          mn[4 * j + l] = fminf(mn[4 * j + l], av[l]);
          mx[4 * j + l] = fmaxf(mx[4 * j + l], av[l]);
        }
      }
    }
    float iv = invd[n];
    bool has = (e1 > e0);
#pragma unroll
    for (int j = 0; j < J; ++j) {
#pragma unroll
      for (int l = 0; l < 4; ++l) {
        int f = 4 * g + 32 * j + l;
        float mean = sm[4 * j + l] * iv;
        float var = sq[4 * j + l] * iv - mean * mean;
        float sd = sqrtf(fmaxf(var, 0.f) + 1e-5f);
        s_agg[r][0 * F + f] = (_Float16)mean;
        s_agg[r][1 * F + f] = (_Float16)(has ? mn[4 * j + l] : 0.f);
        s_agg[r][2 * F + f] = (_Float16)(has ? mx[4 * j + l] : 0.f);
        s_agg[r][3 * F + f] = (_Float16)sd;
      }
    }
  }
  // stage self features as fp16
  for (int idx = tid; idx < 32 * F; idx += 256) {
    int r = idx / F, c = idx - r * F;
    s_x[r][c] = (_Float16)hin[(size_t)(n0 + r) * F + c];
  }
  __syncthreads();

  // ---- Phase B: GEMM.  out = x@W0 + agg@Wa + s1*(agg@Wb) + s2*(agg@Wc) + b ----
  const int w = tid >> 6, ln = tid & 63;
  const int lm = ln & 15, q = ln >> 4;
  const int mt = w & 1;                 // m-tile fixed per wave
  const int arow = mt * 16 + lm;        // A-fragment row (lane&15)
  f32x4 acc0[PPW], acc1[PPW], acc2[PPW];
#pragma unroll
  for (int i = 0; i < PPW; ++i)
#pragma unroll
    for (int t = 0; t < 4; ++t) { acc0[i][t] = 0.f; acc1[i][t] = 0.f; acc2[i][t] = 0.f; }

  // x segment (W rows [0, F))
  for (int k0 = 0; k0 < F; k0 += 32) {
    for (int u = tid; u < FOP * 4; u += 256) {
      int nn = u >> 2, qq = u & 3;
      *(s16x8*)&s_wt[0][nn][8 * qq] = *(const s16x8*)&Wt[(size_t)nn * K13 + k0 + 8 * qq];
    }
    __syncthreads();
    f16x8 a = *(const f16x8*)&s_x[arow][k0 + 8 * q];
#pragma unroll
    for (int i = 0; i < PPW; ++i) {
      int nt = (w >> 1) + 2 * i;
      f16x8 b = *(const f16x8*)&s_wt[0][nt * 16 + lm][8 * q];
      acc0[i] = MFMA16(a, b, acc0[i]);
    }
    __syncthreads();
  }
  // agg segments (W rows [F,5F),[5F,9F),[9F,13F)); one shared A-frag, 3 acc sets
  for (int k0 = 0; k0 < 4 * F; k0 += 32) {
#pragma unroll
    for (int seg = 0; seg < 3; ++seg) {
      const _Float16* src = Wt + F + seg * 4 * F + k0;
      for (int u = tid; u < FOP * 4; u += 256) {
        int nn = u >> 2, qq = u & 3;
        *(s16x8*)&s_wt[seg][nn][8 * qq] = *(const s16x8*)&src[(size_t)nn * K13 + 8 * qq];
      }
    }
    __syncthreads();
    f16x8 a = *(const f16x8*)&s_agg[arow][k0 + 8 * q];
#pragma unroll
    for (int i = 0; i < PPW; ++i) {
      int nt = (w >> 1) + 2 * i;
      const int wrow = nt * 16 + lm;
      f16x8 b0 = *(const f16x8*)&s_wt[0][wrow][8 * q];
      acc0[i] = MFMA16(a, b0, acc0[i]);
      f16x8 b1 = *(const f16x8*)&s_wt[1][wrow][8 * q];
      acc1[i] = MFMA16(a, b1, acc1[i]);
      f16x8 b2 = *(const f16x8*)&s_wt[2][wrow][8 * q];
      acc2[i] = MFMA16(a, b2, acc2[i]);
    }
    __syncthreads();
  }

  // epilogue: D row = (lane>>4)*4 + t, col = lane&15 (verified layout)
  float s1r[4], s2r[4];
#pragma unroll
  for (int t = 0; t < 4; ++t) {
    int node = n0 + mt * 16 + q * 4 + t;
    s1r[t] = s1g[node];
    s2r[t] = s2g[node];
  }
#pragma unroll
  for (int i = 0; i < PPW; ++i) {
    int nt = (w >> 1) + 2 * i;
    int ncol = nt * 16 + lm;
    if (FOP == FO || ncol < FO) {
      float bs = bias[ncol];
#pragma unroll
      for (int t = 0; t < 4; ++t) {
        int node = n0 + mt * 16 + q * 4 + t;
        float v = acc0[i][t] + s1r[t] * acc1[i][t] + s2r[t] * acc2[i][t] + bs;
        if (RELU) v = fmaxf(v, 0.f);
        hout[(size_t)node * FO + ncol] = v;
      }
    }
  }
}

// ---------------- BN stats / apply ----------------
__global__ void k_colstats(const float* __restrict__ h, int n, int fo,
                           float* __restrict__ csum, float* __restrict__ csq) {
  __shared__ float ssum[96], ssq[96];
  int tid = threadIdx.x;
  if (tid < fo) { ssum[tid] = 0.f; ssq[tid] = 0.f; }
  __syncthreads();
  int total = n * fo;
  int T = gridDim.x * 256;
  int i = blockIdx.x * 256 + tid;
  int c = i % fo;
  int step = T % fo;
  for (; i < total; i += T) {
    float v = h[i];
    atomicAdd(&ssum[c], v);
    atomicAdd(&ssq[c], v * v);
    c += step;
    if (c >= fo) c -= fo;
  }
  __syncthreads();
  if (tid < fo) {
    atomicAdd(&csum[tid], ssum[tid]);
    atomicAdd(&csq[tid], ssq[tid]);
  }
}

__global__ void k_bn(float* __restrict__ h, const float* __restrict__ csum,
                     const float* __restrict__ csq, const float* __restrict__ gg,
                     const float* __restrict__ be, int n, int fo, int relu) {
  int i = blockIdx.x * 256 + threadIdx.x;
  if (i >= n * fo) return;
  int c = i % fo;
  float invn = 1.f / (float)n;
  float mu = csum[c] * invn;
  float var = csq[c] * invn - mu * mu;
  float rs = rsqrtf(var + 1e-5f);
  float v = (h[i] - mu) * rs * gg[c] + be[c];
  if (relu) v = fmaxf(v, 0.f);
  h[i] = v;
}

// ---------------- pooling + head ----------------
__global__ void k_pool(const float* __restrict__ h, const int* __restrict__ batch,
                       float* __restrict__ zsum, float* __restrict__ gcnt, int n) {
  __shared__ float sv[NGRAPH * 20];
  __shared__ float sc[NGRAPH];
  int tid = threadIdx.x;
  for (int u = tid; u < NGRAPH * 20; u += 256) sv[u] = 0.f;
  if (tid < NGRAPH) sc[tid] = 0.f;
  __syncthreads();
  int i = blockIdx.x * 256 + tid;
  if (i < n) {
    int g = batch[i];
    atomicAdd(&sc[g], 1.f);
    for (int j = 0; j < 20; ++j) atomicAdd(&sv[g * 20 + j], h[(size_t)i * 20 + j]);
  }
  __syncthreads();
  if (tid < NGRAPH && sc[tid] != 0.f) {
    atomicAdd(&gcnt[tid], sc[tid]);
    for (int j = 0; j < 20; ++j) atomicAdd(&zsum[tid * 20 + j], sv[tid * 20 + j]);
  }
}

__global__ void k_head(const float* __restrict__ zsum, const float* __restrict__ gcnt,
                       const float* __restrict__ wl, const float* __restrict__ bl,
                       float* __restrict__ out) {
  int g = threadIdx.x;
  if (g >= NGRAPH) return;
  float z[20];
  float icg = 1.f / fmaxf(gcnt[g], 1.f);
#pragma unroll
  for (int j = 0; j < 20; ++j) {
    z[j] = zsum[g * 20 + j] * icg;
    out[NGRAPH * 11 + g * 20 + j] = z[j];  // second output: z
  }
  float lo[11];
#pragma unroll
  for (int o = 0; o < 11; ++o) {
    float a = bl[o];
    for (int j = 0; j < 20; ++j) a += z[j] * wl[j * 11 + o];
    lo[o] = a;
  }
  float m = lo[0];
  for (int o = 1; o < 11; ++o) m = fmaxf(m, lo[o]);
  float s = 0.f;
  for (int o = 0; o < 11; ++o) { lo[o] = expf(lo[o] - m); s += lo[o]; }
  float is = 1.f / s;
  for (int o = 0; o < 11; ++o) out[g * 11 + o] = lo[o] * is;  // first output: softmax
}

// ---------------- launch ----------------
static inline char* carve(char*& p, size_t bytes) {
  char* r = p;
  p += (bytes + 255) & ~(size_t)255;
  return r;
}

extern "C" void kernel_launch(void* const* d_in, const int* in_sizes, int n_in,
                              void* d_out, int out_size, void* d_ws, size_t ws_size,
                              hipStream_t stream) {
  const float* x = (const float*)d_in[0];
  const int* ei = (const int*)d_in[1];
  const int* batch = (const int*)d_in[2];
  const float* W0 = (const float*)d_in[3];
  const float* b0 = (const float*)d_in[4];
  const float* W1 = (const float*)d_in[5];
  const float* b1 = (const float*)d_in[6];
  const float* W2 = (const float*)d_in[7];
  const float* b2 = (const float*)d_in[8];
  const float* W3 = (const float*)d_in[9];
  const float* b3 = (const float*)d_in[10];
  const float* g0 = (const float*)d_in[11];
  const float* be0 = (const float*)d_in[12];
  const float* g1 = (const float*)d_in[13];
  const float* be1 = (const float*)d_in[14];
  const float* g2 = (const float*)d_in[15];
  const float* be2 = (const float*)d_in[16];
  const float* wl = (const float*)d_in[17];
  const float* bl = (const float*)d_in[18];
  float* out = (float*)d_out;

  const int E = in_sizes[1] / 2;       // 3200000
  const int NB = (NN + 255) / 256;     // 391

  char* p = (char*)d_ws;
  int* cnt = (int*)carve(p, (size_t)NN * 4);
  int* row_ptr = (int*)carve(p, (size_t)(NN + 1) * 4);
  int* cursor = (int*)carve(p, (size_t)NN * 4);
  int* bsum = (int*)carve(p, 2048);
  int* boff = (int*)carve(p, 2048);
  int* colv = (int*)carve(p, (size_t)E * 4);
  float* invd = (float*)carve(p, (size_t)NN * 4);
  float* s1v = (float*)carve(p, (size_t)NN * 4);
  float* s2v = (float*)carve(p, (size_t)NN * 4);
  _Float16* Wt0 = (_Float16*)carve(p, (size_t)96 * 832 * 2);
  _Float16* Wt1 = (_Float16*)carve(p, (size_t)64 * 1248 * 2);
  _Float16* Wt2 = (_Float16*)carve(p, (size_t)32 * 832 * 2);
  _Float16* Wt3 = (_Float16*)carve(p, (size_t)32 * 416 * 2);
  float* cs = (float*)carve(p, 192 * 4);  // csum[96] + csq[96]
  float* csum = cs;
  float* csq = cs + 96;
  float* pacc = (float*)carve(p, (NGRAPH * 20 + NGRAPH) * 4);  // zsum + gcnt
  float* zsum = pacc;
  float* gcnt = pacc + NGRAPH * 20;
  float* hbA = (float*)carve(p, (size_t)NN * 96 * 4);
  float* hbB = (float*)carve(p, (size_t)NN * 96 * 4);

  // CSR + per-node scalars
  hipMemsetAsync(cnt, 0, (size_t)NN * 4, stream);
  hipMemsetAsync(pacc, 0, (NGRAPH * 20 + NGRAPH) * 4, stream);
  k_degree<<<(E + 255) / 256, 256, 0, stream>>>(ei, cnt, E);
  k_blocksum<<<NB, 256, 0, stream>>>(cnt, bsum, NN);
  k_scanb<<<1, 512, 0, stream>>>(bsum, boff, NB);
  k_scatter<<<NB, 256, 0, stream>>>(cnt, boff, row_ptr, NN, E);
  k_nodesc<<<NB, 256, 0, stream>>>(cnt, row_ptr, cursor, invd, s1v, s2v, NN);
  k_fill<<<(E + 255) / 256, 256, 0, stream>>>(ei, cursor, colv, E);

  // fp16 transposed weights
  k_wtprep<<<(96 * 832 + 255) / 256, 256, 0, stream>>>(W0, Wt0, 832, 96, 96);
  k_wtprep<<<(64 * 1248 + 255) / 256, 256, 0, stream>>>(W1, Wt1, 1248, 64, 64);
  k_wtprep<<<(32 * 832 + 255) / 256, 256, 0, stream>>>(W2, Wt2, 832, 32, 32);
  k_wtprep<<<(32 * 416 + 255) / 256, 256, 0, stream>>>(W3, Wt3, 416, 20, 32);

  const int GP = NN / 32;  // 3125

  // Layer 0: (64 -> 96), BN + ReLU
  k_pna<64, 96, 96, false><<<GP, 256, 0, stream>>>(x, row_ptr, colv, invd, s1v, s2v, Wt0, b0, hbA);
  hipMemsetAsync(cs, 0, 192 * 4, stream);
  k_colstats<<<512, 256, 0, stream>>>(hbA, NN, 96, csum, csq);
  k_bn<<<(NN * 96 + 255) / 256, 256, 0, stream>>>(hbA, csum, csq, g0, be0, NN, 96, 1);

  // Layer 1: (96 -> 64), BN + ReLU
  k_pna<96, 64, 64, false><<<GP, 256, 0, stream>>>(hbA, row_ptr, colv, invd, s1v, s2v, Wt1, b1, hbB);
  hipMemsetAsync(cs, 0, 192 * 4, stream);
  k_colstats<<<512, 256, 0, stream>>>(hbB, NN, 64, csum, csq);
  k_bn<<<(NN * 64 + 255) / 256, 256, 0, stream>>>(hbB, csum, csq, g1, be1, NN, 64, 1);

  // Layer 2: (64 -> 32), ReLU only (fused in epilogue)
  k_pna<64, 32, 32, true><<<GP, 256, 0, stream>>>(hbB, row_ptr, colv, invd, s1v, s2v, Wt2, b2, hbA);

  // Layer 3: (32 -> 20), BN (no ReLU)
  k_pna<32, 20, 32, false><<<GP, 256, 0, stream>>>(hbA, row_ptr, colv, invd, s1v, s2v, Wt3, b3, hbB);
  hipMemsetAsync(cs, 0, 192 * 4, stream);
  k_colstats<<<512, 256, 0, stream>>>(hbB, NN, 20, csum, csq);
  k_bn<<<(NN * 20 + 255) / 256, 256, 0, stream>>>(hbB, csum, csq, g2, be2, NN, 20, 0);

  // global mean pool + linear + softmax
  k_pool<<<NB, 256, 0, stream>>>(hbB, batch, zsum, gcnt, NN);
  k_head<<<1, 64, 0, stream>>>(zsum, gcnt, wl, bl, out);
}

// Round 4
// 1180.462 us; speedup vs baseline: 1.2081x; 1.2081x over previous
//
#include <hip/hip_runtime.h>

#define NN 100000
#define NGRAPH 64
#define NPART 8
#define AVGLOG 3.4965075614664802f

using f32x4 = __attribute__((ext_vector_type(4))) float;
using s16x8 = __attribute__((ext_vector_type(8))) short;
using f16x8 = __attribute__((ext_vector_type(8))) _Float16;
using f16x4 = __attribute__((ext_vector_type(4))) _Float16;

// ---------------- CSR build ----------------
__global__ void k_degree(const int* __restrict__ ei, int* __restrict__ cnt, int E) {
  int e = blockIdx.x * 256 + threadIdx.x;
  if (e < E) atomicAdd(&cnt[ei[E + e]], 1);
}

__global__ void k_blocksum(const int* __restrict__ cnt, int* __restrict__ bsum, int n) {
  __shared__ int s[256];
  int i = blockIdx.x * 256 + threadIdx.x;
  s[threadIdx.x] = (i < n) ? cnt[i] : 0;
  __syncthreads();
  for (int off = 128; off > 0; off >>= 1) {
    if (threadIdx.x < off) s[threadIdx.x] += s[threadIdx.x + off];
    __syncthreads();
  }
  if (threadIdx.x == 0) bsum[blockIdx.x] = s[0];
}

__global__ void k_scanb(const int* __restrict__ bsum, int* __restrict__ boff, int nb) {
  __shared__ int s[512];
  int t = threadIdx.x;
  int v = (t < nb) ? bsum[t] : 0;
  s[t] = v;
  __syncthreads();
  for (int off = 1; off < 512; off <<= 1) {
    int u = (t >= off) ? s[t - off] : 0;
    __syncthreads();
    s[t] += u;
    __syncthreads();
  }
  if (t < nb) boff[t] = s[t] - v;  // exclusive block offsets
}

__global__ void k_scatter(const int* __restrict__ cnt, const int* __restrict__ boff,
                          int* __restrict__ row_ptr, int n, int etot) {
  __shared__ int s[256];
  int i = blockIdx.x * 256 + threadIdx.x;
  int v = (i < n) ? cnt[i] : 0;
  s[threadIdx.x] = v;
  __syncthreads();
  for (int off = 1; off < 256; off <<= 1) {
    int u = (threadIdx.x >= off) ? s[threadIdx.x - off] : 0;
    __syncthreads();
    s[threadIdx.x] += u;
    __syncthreads();
  }
  if (i < n) row_ptr[i] = boff[blockIdx.x] + s[threadIdx.x] - v;
  if (i == 0) row_ptr[n] = etot;
}

__global__ void k_nodesc(const int* __restrict__ cnt, const int* __restrict__ row_ptr,
                         int* __restrict__ cursor, float* __restrict__ invd,
                         float* __restrict__ s1v, float* __restrict__ s2v, int n) {
  int i = blockIdx.x * 256 + threadIdx.x;
  if (i >= n) return;
  cursor[i] = row_ptr[i];
  float degc = fmaxf((float)cnt[i], 1.f);
  invd[i] = 1.f / degc;
  float ld = logf(degc + 1.f);
  s1v[i] = ld * (1.f / AVGLOG);
  s2v[i] = AVGLOG / ld;
}

// Partitioned fill: partition = blockIdx & 7 (XCD round-robin). Each partition
// scans all dst (coalesced, L3-hit) but only scatters edges landing in its
// 12.5K-node window -> colv writes confined to ~1.6MB (one XCD L2).
__global__ void k_fillp(const int* __restrict__ ei, int* __restrict__ cursor,
                        int* __restrict__ colv, int E) {
  const int part = blockIdx.x & (NPART - 1);
  const int lo = part * (NN / NPART), hi = lo + (NN / NPART);
  const int nch = gridDim.x >> 3;
  const int ch = blockIdx.x >> 3;
  const int stride = nch * 256;
  for (int e = ch * 256 + threadIdx.x; e < E; e += stride) {
    int d = ei[E + e];
    if (d >= lo && d < hi) {
      int pos = atomicAdd(&cursor[d], 1);
      colv[pos] = ei[e];
    }
  }
}

// W [K][FO] fp32 -> Wt [FOP][K] fp16 (rows >= FO zero-padded)
__global__ void k_wtprep(const float* __restrict__ W, _Float16* __restrict__ Wt,
                         int K, int FO, int FOP) {
  int i = blockIdx.x * 256 + threadIdx.x;
  if (i >= FOP * K) return;
  int nn = i / K, k = i - nn * K;
  float v = (nn < FO) ? W[k * FO + nn] : 0.f;
  Wt[i] = (_Float16)v;
}

__global__ void k_xconv(const float* __restrict__ x, _Float16* __restrict__ x16, int n) {
  int i = blockIdx.x * 256 + threadIdx.x;
  if (i < n) x16[i] = (_Float16)x[i];
}

// ---------------- fused PNA layer: aggregate + 13F GEMM (fp16 MFMA) ----------------
#define MFMA16(a, b, c) __builtin_amdgcn_mfma_f32_16x16x32_f16(a, b, c, 0, 0, 0)

template <int F, int FO, int FOP, bool RELU, typename OT>
__launch_bounds__(256)
__global__ void k_pna(const _Float16* __restrict__ hin, const int* __restrict__ row_ptr,
                      const int* __restrict__ colv, const float* __restrict__ invd,
                      const float* __restrict__ s1g, const float* __restrict__ s2g,
                      const _Float16* __restrict__ Wt, const float* __restrict__ bias,
                      OT* __restrict__ hout) {
  constexpr int K13 = 13 * F;
  constexpr int AGW = 4 * F + 8;   // halves; row bytes = (4F+8)*2, 16B multiple
  constexpr int XW = F + 8;
  constexpr int NT = FOP / 16;
  constexpr int PPW = (2 * NT) / 4;  // tile-pairs per wave
  __shared__ __align__(16) _Float16 s_agg[32][AGW];
  __shared__ __align__(16) _Float16 s_x[32][XW];
  __shared__ __align__(16) _Float16 s_wt[3][FOP][40];

  const int tid = threadIdx.x;
  const int n0 = blockIdx.x * 32;

  // ---- Phase A: aggregation (8 threads/node, per-thread contiguous F/8 halves) ----
  {
    const int r = tid >> 3, g = tid & 7;
    const int n = n0 + r;
    const int e0 = row_ptr[n], e1 = row_ptr[n + 1];
    constexpr int SEG = F / 8;        // halves per thread: 8 / 12 / 4
    constexpr int SEG4 = SEG / 4;     // f16x4 loads per row: 2 / 3 / 1
    float sm[SEG], sq[SEG], mn[SEG], mx[SEG];
    const float FINF = __builtin_inff();
#pragma unroll
    for (int j = 0; j < SEG; ++j) { sm[j] = 0.f; sq[j] = 0.f; mn[j] = FINF; mx[j] = -FINF; }
    int e = e0;
    for (; e + 1 < e1; e += 2) {
      int sA = colv[e], sB = colv[e + 1];
      const f16x4* ra = (const f16x4*)(hin + (size_t)sA * F + g * SEG);
      const f16x4* rb = (const f16x4*)(hin + (size_t)sB * F + g * SEG);
#pragma unroll
      for (int c = 0; c < SEG4; ++c) {
        f16x4 va = ra[c], vb = rb[c];
#pragma unroll
        for (int l = 0; l < 4; ++l) {
          float av = (float)va[l], bv = (float)vb[l];
          int j = 4 * c + l;
          sm[j] += av + bv;
          sq[j] += av * av + bv * bv;
          mn[j] = fminf(mn[j], fminf(av, bv));
          mx[j] = fmaxf(mx[j], fmaxf(av, bv));
        }
      }
    }
    if (e < e1) {
      int sA = colv[e];
      const f16x4* ra = (const f16x4*)(hin + (size_t)sA * F + g * SEG);
#pragma unroll
      for (int c = 0; c < SEG4; ++c) {
        f16x4 va = ra[c];
#pragma unroll
        for (int l = 0; l < 4; ++l) {
          float av = (float)va[l];
          int j = 4 * c + l;
          sm[j] += av;
          sq[j] += av * av;
          mn[j] = fminf(mn[j], av);
          mx[j] = fmaxf(mx[j], av);
        }
      }
    }
    float iv = invd[n];
    bool has = (e1 > e0);
#pragma unroll
    for (int j = 0; j < SEG; ++j) {
      int f = g * SEG + j;
      float mean = sm[j] * iv;
      float var = sq[j] * iv - mean * mean;
      float sd = sqrtf(fmaxf(var, 0.f) + 1e-5f);
      s_agg[r][0 * F + f] = (_Float16)mean;
      s_agg[r][1 * F + f] = has ? (_Float16)mn[j] : (_Float16)0.f;
      s_agg[r][2 * F + f] = has ? (_Float16)mx[j] : (_Float16)0.f;
      s_agg[r][3 * F + f] = (_Float16)sd;
    }
  }
  // stage self features
  for (int idx = tid; idx < 32 * F; idx += 256) {
    int r = idx / F, c = idx - r * F;
    s_x[r][c] = hin[(size_t)(n0 + r) * F + c];
  }
  __syncthreads();

  // ---- Phase B: GEMM.  out = x@W0 + agg@Wa + s1*(agg@Wb) + s2*(agg@Wc) + b ----
  const int w = tid >> 6, ln = tid & 63;
  const int lm = ln & 15, q = ln >> 4;
  const int mt = w & 1;
  const int arow = mt * 16 + lm;
  f32x4 acc0[PPW], acc1[PPW], acc2[PPW];
#pragma unroll
  for (int i = 0; i < PPW; ++i)
#pragma unroll
    for (int t = 0; t < 4; ++t) { acc0[i][t] = 0.f; acc1[i][t] = 0.f; acc2[i][t] = 0.f; }

  // x segment (W rows [0, F))
  for (int k0 = 0; k0 < F; k0 += 32) {
    for (int u = tid; u < FOP * 4; u += 256) {
      int nn = u >> 2, qq = u & 3;
      *(f16x8*)&s_wt[0][nn][8 * qq] = *(const f16x8*)&Wt[(size_t)nn * K13 + k0 + 8 * qq];
    }
    __syncthreads();
    f16x8 a = *(const f16x8*)&s_x[arow][k0 + 8 * q];
#pragma unroll
    for (int i = 0; i < PPW; ++i) {
      int nt = (w >> 1) + 2 * i;
      f16x8 b = *(const f16x8*)&s_wt[0][nt * 16 + lm][8 * q];
      acc0[i] = MFMA16(a, b, acc0[i]);
    }
    __syncthreads();
  }
  // agg segments (W rows [F,5F),[5F,9F),[9F,13F)); one shared A-frag, 3 acc sets
  for (int k0 = 0; k0 < 4 * F; k0 += 32) {
#pragma unroll
    for (int seg = 0; seg < 3; ++seg) {
      const _Float16* src = Wt + F + seg * 4 * F + k0;
      for (int u = tid; u < FOP * 4; u += 256) {
        int nn = u >> 2, qq = u & 3;
        *(f16x8*)&s_wt[seg][nn][8 * qq] = *(const f16x8*)&src[(size_t)nn * K13 + 8 * qq];
      }
    }
    __syncthreads();
    f16x8 a = *(const f16x8*)&s_agg[arow][k0 + 8 * q];
#pragma unroll
    for (int i = 0; i < PPW; ++i) {
      int nt = (w >> 1) + 2 * i;
      const int wrow = nt * 16 + lm;
      f16x8 b0 = *(const f16x8*)&s_wt[0][wrow][8 * q];
      acc0[i] = MFMA16(a, b0, acc0[i]);
      f16x8 b1 = *(const f16x8*)&s_wt[1][wrow][8 * q];
      acc1[i] = MFMA16(a, b1, acc1[i]);
      f16x8 b2 = *(const f16x8*)&s_wt[2][wrow][8 * q];
      acc2[i] = MFMA16(a, b2, acc2[i]);
    }
    __syncthreads();
  }

  // epilogue: D row = (lane>>4)*4 + t, col = lane&15
  float s1r[4], s2r[4];
#pragma unroll
  for (int t = 0; t < 4; ++t) {
    int node = n0 + mt * 16 + q * 4 + t;
    s1r[t] = s1g[node];
    s2r[t] = s2g[node];
  }
#pragma unroll
  for (int i = 0; i < PPW; ++i) {
    int nt = (w >> 1) + 2 * i;
    int ncol = nt * 16 + lm;
    if (FOP == FO || ncol < FO) {
      float bs = bias[ncol];
#pragma unroll
      for (int t = 0; t < 4; ++t) {
        int node = n0 + mt * 16 + q * 4 + t;
        float v = acc0[i][t] + s1r[t] * acc1[i][t] + s2r[t] * acc2[i][t] + bs;
        if (RELU) v = fmaxf(v, 0.f);
        hout[(size_t)node * FO + ncol] = (OT)v;
      }
    }
  }
}

// ---------------- BN stats / apply (templated element type) ----------------
template <typename T>
__global__ void k_colstats(const T* __restrict__ h, int n, int fo,
                           float* __restrict__ csum, float* __restrict__ csq) {
  __shared__ float ssum[96], ssq[96];
  int tid = threadIdx.x;
  if (tid < fo) { ssum[tid] = 0.f; ssq[tid] = 0.f; }
  __syncthreads();
  int total = n * fo;
  int T2 = gridDim.x * 256;
  int i = blockIdx.x * 256 + tid;
  int c = i % fo;
  int step = T2 % fo;
  for (; i < total; i += T2) {
    float v = (float)h[i];
    atomicAdd(&ssum[c], v);
    atomicAdd(&ssq[c], v * v);
    c += step;
    if (c >= fo) c -= fo;
  }
  __syncthreads();
  if (tid < fo) {
    atomicAdd(&csum[tid], ssum[tid]);
    atomicAdd(&csq[tid], ssq[tid]);
  }
}

template <typename T>
__global__ void k_bn(T* __restrict__ h, const float* __restrict__ csum,
                     const float* __restrict__ csq, const float* __restrict__ gg,
                     const float* __restrict__ be, int n, int fo, int relu) {
  int i = blockIdx.x * 256 + threadIdx.x;
  if (i >= n * fo) return;
  int c = i % fo;
  float invn = 1.f / (float)n;
  float mu = csum[c] * invn;
  float var = csq[c] * invn - mu * mu;
  float rs = rsqrtf(var + 1e-5f);
  float v = ((float)h[i] - mu) * rs * gg[c] + be[c];
  if (relu) v = fmaxf(v, 0.f);
  h[i] = (T)v;
}

// ---------------- pooling + head ----------------
__global__ void k_pool(const float* __restrict__ h, const int* __restrict__ batch,
                       float* __restrict__ zsum, float* __restrict__ gcnt, int n) {
  __shared__ float sv[NGRAPH * 20];
  __shared__ float sc[NGRAPH];
  int tid = threadIdx.x;
  for (int u = tid; u < NGRAPH * 20; u += 256) sv[u] = 0.f;
  if (tid < NGRAPH) sc[tid] = 0.f;
  __syncthreads();
  int i = blockIdx.x * 256 + tid;
  if (i < n) {
    int g = batch[i];
    atomicAdd(&sc[g], 1.f);
    for (int j = 0; j < 20; ++j) atomicAdd(&sv[g * 20 + j], h[(size_t)i * 20 + j]);
  }
  __syncthreads();
  if (tid < NGRAPH && sc[tid] != 0.f) {
    atomicAdd(&gcnt[tid], sc[tid]);
    for (int j = 0; j < 20; ++j) atomicAdd(&zsum[tid * 20 + j], sv[tid * 20 + j]);
  }
}

__global__ void k_head(const float* __restrict__ zsum, const float* __restrict__ gcnt,
                       const float* __restrict__ wl, const float* __restrict__ bl,
                       float* __restrict__ out) {
  int g = threadIdx.x;
  if (g >= NGRAPH) return;
  float z[20];
  float icg = 1.f / fmaxf(gcnt[g], 1.f);
#pragma unroll
  for (int j = 0; j < 20; ++j) {
    z[j] = zsum[g * 20 + j] * icg;
    out[NGRAPH * 11 + g * 20 + j] = z[j];  // second output: z
  }
  float lo[11];
#pragma unroll
  for (int o = 0; o < 11; ++o) {
    float a = bl[o];
    for (int j = 0; j < 20; ++j) a += z[j] * wl[j * 11 + o];
    lo[o] = a;
  }
  float m = lo[0];
  for (int o = 1; o < 11; ++o) m = fmaxf(m, lo[o]);
  float s = 0.f;
  for (int o = 0; o < 11; ++o) { lo[o] = expf(lo[o] - m); s += lo[o]; }
  float is = 1.f / s;
  for (int o = 0; o < 11; ++o) out[g * 11 + o] = lo[o] * is;  // first output: softmax
}

// ---------------- launch ----------------
static inline char* carve(char*& p, size_t bytes) {
  char* r = p;
  p += (bytes + 255) & ~(size_t)255;
  return r;
}

extern "C" void kernel_launch(void* const* d_in, const int* in_sizes, int n_in,
                              void* d_out, int out_size, void* d_ws, size_t ws_size,
                              hipStream_t stream) {
  const float* x = (const float*)d_in[0];
  const int* ei = (const int*)d_in[1];
  const int* batch = (const int*)d_in[2];
  const float* W0 = (const float*)d_in[3];
  const float* b0 = (const float*)d_in[4];
  const float* W1 = (const float*)d_in[5];
  const float* b1 = (const float*)d_in[6];
  const float* W2 = (const float*)d_in[7];
  const float* b2 = (const float*)d_in[8];
  const float* W3 = (const float*)d_in[9];
  const float* b3 = (const float*)d_in[10];
  const float* g0 = (const float*)d_in[11];
  const float* be0 = (const float*)d_in[12];
  const float* g1 = (const float*)d_in[13];
  const float* be1 = (const float*)d_in[14];
  const float* g2 = (const float*)d_in[15];
  const float* be2 = (const float*)d_in[16];
  const float* wl = (const float*)d_in[17];
  const float* bl = (const float*)d_in[18];
  float* out = (float*)d_out;

  const int E = in_sizes[1] / 2;       // 3200000
  const int NB = (NN + 255) / 256;     // 391

  char* p = (char*)d_ws;
  int* cnt = (int*)carve(p, (size_t)NN * 4);
  int* row_ptr = (int*)carve(p, (size_t)(NN + 1) * 4);
  int* cursor = (int*)carve(p, (size_t)NN * 4);
  int* bsum = (int*)carve(p, 2048);
  int* boff = (int*)carve(p, 2048);
  int* colv = (int*)carve(p, (size_t)E * 4);
  float* invd = (float*)carve(p, (size_t)NN * 4);
  float* s1v = (float*)carve(p, (size_t)NN * 4);
  float* s2v = (float*)carve(p, (size_t)NN * 4);
  _Float16* Wt0 = (_Float16*)carve(p, (size_t)96 * 832 * 2);
  _Float16* Wt1 = (_Float16*)carve(p, (size_t)64 * 1248 * 2);
  _Float16* Wt2 = (_Float16*)carve(p, (size_t)32 * 832 * 2);
  _Float16* Wt3 = (_Float16*)carve(p, (size_t)32 * 416 * 2);
  float* cs = (float*)carve(p, 192 * 4);
  float* csum = cs;
  float* csq = cs + 96;
  float* pacc = (float*)carve(p, (NGRAPH * 20 + NGRAPH) * 4);
  float* zsum = pacc;
  float* gcnt = pacc + NGRAPH * 20;
  _Float16* x16 = (_Float16*)carve(p, (size_t)NN * 64 * 2);
  _Float16* hA16 = (_Float16*)carve(p, (size_t)NN * 96 * 2);
  _Float16* hB16 = (_Float16*)carve(p, (size_t)NN * 96 * 2);
  float* h3 = (float*)carve(p, (size_t)NN * 20 * 4);

  // CSR + per-node scalars
  hipMemsetAsync(cnt, 0, (size_t)NN * 4, stream);
  hipMemsetAsync(pacc, 0, (NGRAPH * 20 + NGRAPH) * 4, stream);
  k_degree<<<(E + 255) / 256, 256, 0, stream>>>(ei, cnt, E);
  k_blocksum<<<NB, 256, 0, stream>>>(cnt, bsum, NN);
  k_scanb<<<1, 512, 0, stream>>>(bsum, boff, NB);
  k_scatter<<<NB, 256, 0, stream>>>(cnt, boff, row_ptr, NN, E);
  k_nodesc<<<NB, 256, 0, stream>>>(cnt, row_ptr, cursor, invd, s1v, s2v, NN);
  k_fillp<<<NPART * 256, 256, 0, stream>>>(ei, cursor, colv, E);

  // fp16 transposed weights + fp16 x
  k_wtprep<<<(96 * 832 + 255) / 256, 256, 0, stream>>>(W0, Wt0, 832, 96, 96);
  k_wtprep<<<(64 * 1248 + 255) / 256, 256, 0, stream>>>(W1, Wt1, 1248, 64, 64);
  k_wtprep<<<(32 * 832 + 255) / 256, 256, 0, stream>>>(W2, Wt2, 832, 32, 32);
  k_wtprep<<<(32 * 416 + 255) / 256, 256, 0, stream>>>(W3, Wt3, 416, 20, 32);
  k_xconv<<<(NN * 64 + 255) / 256, 256, 0, stream>>>(x, x16, NN * 64);

  const int GP = NN / 32;  // 3125

  // Layer 0: (64 -> 96), BN + ReLU
  k_pna<64, 96, 96, false, _Float16><<<GP, 256, 0, stream>>>(x16, row_ptr, colv, invd, s1v, s2v, Wt0, b0, hA16);
  hipMemsetAsync(cs, 0, 192 * 4, stream);
  k_colstats<_Float16><<<512, 256, 0, stream>>>(hA16, NN, 96, csum, csq);
  k_bn<_Float16><<<(NN * 96 + 255) / 256, 256, 0, stream>>>(hA16, csum, csq, g0, be0, NN, 96, 1);

  // Layer 1: (96 -> 64), BN + ReLU
  k_pna<96, 64, 64, false, _Float16><<<GP, 256, 0, stream>>>(hA16, row_ptr, colv, invd, s1v, s2v, Wt1, b1, hB16);
  hipMemsetAsync(cs, 0, 192 * 4, stream);
  k_colstats<_Float16><<<512, 256, 0, stream>>>(hB16, NN, 64, csum, csq);
  k_bn<_Float16><<<(NN * 64 + 255) / 256, 256, 0, stream>>>(hB16, csum, csq, g1, be1, NN, 64, 1);

  // Layer 2: (64 -> 32), ReLU only (fused in epilogue)
  k_pna<64, 32, 32, true, _Float16><<<GP, 256, 0, stream>>>(hB16, row_ptr, colv, invd, s1v, s2v, Wt2, b2, hA16);

  // Layer 3: (32 -> 20), BN (no ReLU), fp32 out (feeds pooling)
  k_pna<32, 20, 32, false, float><<<GP, 256, 0, stream>>>(hA16, row_ptr, colv, invd, s1v, s2v, Wt3, b3, h3);
  hipMemsetAsync(cs, 0, 192 * 4, stream);
  k_colstats<float><<<512, 256, 0, stream>>>(h3, NN, 20, csum, csq);
  k_bn<float><<<(NN * 20 + 255) / 256, 256, 0, stream>>>(h3, csum, csq, g2, be2, NN, 20, 0);

  // global mean pool + linear + softmax
  k_pool<<<NB, 256, 0, stream>>>(h3, batch, zsum, gcnt, NN);
  k_head<<<1, 64, 0, stream>>>(zsum, gcnt, wl, bl, out);
}

// Round 5
// 1128.902 us; speedup vs baseline: 1.2633x; 1.0457x over previous
//
#include <hip/hip_runtime.h>

#define NN 100000
#define NGRAPH 64
#define NPART 8
#define AVGLOG 3.4965075614664802f

using f32x4 = __attribute__((ext_vector_type(4))) float;
using f16x8 = __attribute__((ext_vector_type(8))) _Float16;
using f16x4 = __attribute__((ext_vector_type(4))) _Float16;

// ---------------- CSR build ----------------
__global__ void k_degree(const int* __restrict__ ei, int* __restrict__ cnt, int E) {
  int e = blockIdx.x * 256 + threadIdx.x;
  if (e < E) atomicAdd(&cnt[ei[E + e]], 1);
}

__global__ void k_blocksum(const int* __restrict__ cnt, int* __restrict__ bsum, int n) {
  __shared__ int s[256];
  int i = blockIdx.x * 256 + threadIdx.x;
  s[threadIdx.x] = (i < n) ? cnt[i] : 0;
  __syncthreads();
  for (int off = 128; off > 0; off >>= 1) {
    if (threadIdx.x < off) s[threadIdx.x] += s[threadIdx.x + off];
    __syncthreads();
  }
  if (threadIdx.x == 0) bsum[blockIdx.x] = s[0];
}

__global__ void k_scanb(const int* __restrict__ bsum, int* __restrict__ boff, int nb) {
  __shared__ int s[512];
  int t = threadIdx.x;
  int v = (t < nb) ? bsum[t] : 0;
  s[t] = v;
  __syncthreads();
  for (int off = 1; off < 512; off <<= 1) {
    int u = (t >= off) ? s[t - off] : 0;
    __syncthreads();
    s[t] += u;
    __syncthreads();
  }
  if (t < nb) boff[t] = s[t] - v;  // exclusive block offsets
}

__global__ void k_scatter(const int* __restrict__ cnt, const int* __restrict__ boff,
                          int* __restrict__ row_ptr, int n, int etot) {
  __shared__ int s[256];
  int i = blockIdx.x * 256 + threadIdx.x;
  int v = (i < n) ? cnt[i] : 0;
  s[threadIdx.x] = v;
  __syncthreads();
  for (int off = 1; off < 256; off <<= 1) {
    int u = (threadIdx.x >= off) ? s[threadIdx.x - off] : 0;
    __syncthreads();
    s[threadIdx.x] += u;
    __syncthreads();
  }
  if (i < n) row_ptr[i] = boff[blockIdx.x] + s[threadIdx.x] - v;
  if (i == 0) row_ptr[n] = etot;
}

__global__ void k_nodesc(const int* __restrict__ cnt, const int* __restrict__ row_ptr,
                         int* __restrict__ cursor, float* __restrict__ invd,
                         float* __restrict__ s1v, float* __restrict__ s2v, int n) {
  int i = blockIdx.x * 256 + threadIdx.x;
  if (i >= n) return;
  cursor[i] = row_ptr[i];
  float degc = fmaxf((float)cnt[i], 1.f);
  invd[i] = 1.f / degc;
  float ld = logf(degc + 1.f);
  s1v[i] = ld * (1.f / AVGLOG);
  s2v[i] = AVGLOG / ld;
}

// Partitioned fill: writes confined to ~1.6MB window per partition (one XCD L2)
__global__ void k_fillp(const int* __restrict__ ei, int* __restrict__ cursor,
                        int* __restrict__ colv, int E) {
  const int part = blockIdx.x & (NPART - 1);
  const int lo = part * (NN / NPART), hi = lo + (NN / NPART);
  const int nch = gridDim.x >> 3;
  const int ch = blockIdx.x >> 3;
  const int stride = nch * 256;
  for (int e = ch * 256 + threadIdx.x; e < E; e += stride) {
    int d = ei[E + e];
    if (d >= lo && d < hi) {
      int pos = atomicAdd(&cursor[d], 1);
      colv[pos] = ei[e];
    }
  }
}

// W [K][FO] fp32 -> Wt [FOP][K] fp16 (rows >= FO zero-padded)
__global__ void k_wtprep(const float* __restrict__ W, _Float16* __restrict__ Wt,
                         int K, int FO, int FOP) {
  int i = blockIdx.x * 256 + threadIdx.x;
  if (i >= FOP * K) return;
  int nn = i / K, k = i - nn * K;
  float v = (nn < FO) ? W[k * FO + nn] : 0.f;
  Wt[i] = (_Float16)v;
}

__global__ void k_xconv(const float* __restrict__ x, _Float16* __restrict__ x16, int n) {
  int i = blockIdx.x * 256 + threadIdx.x;
  if (i < n) x16[i] = (_Float16)x[i];
}

// ---------------- Phase A standalone: high-occupancy gather/reduce ----------------
// 8 threads/node, no LDS; WPE tunes VGPR cap for occupancy.
template <int F, int WPE>
__launch_bounds__(256, WPE)
__global__ void k_agg(const _Float16* __restrict__ hin, const int* __restrict__ row_ptr,
                      const int* __restrict__ colv, const float* __restrict__ invd,
                      _Float16* __restrict__ agg) {
  const int tid = threadIdx.x;
  const int r = tid >> 3, g = tid & 7;
  const int n = blockIdx.x * 32 + r;
  const int e0 = row_ptr[n], e1 = row_ptr[n + 1];
  constexpr int SEG = F / 8;
  constexpr int SEG4 = SEG / 4;
  float sm[SEG], sq[SEG], mn[SEG], mx[SEG];
  const float FINF = __builtin_inff();
#pragma unroll
  for (int j = 0; j < SEG; ++j) { sm[j] = 0.f; sq[j] = 0.f; mn[j] = FINF; mx[j] = -FINF; }
  int e = e0;
  for (; e + 1 < e1; e += 2) {
    int sA = colv[e], sB = colv[e + 1];
    const f16x4* ra = (const f16x4*)(hin + (size_t)sA * F + g * SEG);
    const f16x4* rb = (const f16x4*)(hin + (size_t)sB * F + g * SEG);
#pragma unroll
    for (int c = 0; c < SEG4; ++c) {
      f16x4 va = ra[c], vb = rb[c];
#pragma unroll
      for (int l = 0; l < 4; ++l) {
        float av = (float)va[l], bv = (float)vb[l];
        int j = 4 * c + l;
        sm[j] += av + bv;
        sq[j] += av * av + bv * bv;
        mn[j] = fminf(mn[j], fminf(av, bv));
        mx[j] = fmaxf(mx[j], fmaxf(av, bv));
      }
    }
  }
  if (e < e1) {
    int sA = colv[e];
    const f16x4* ra = (const f16x4*)(hin + (size_t)sA * F + g * SEG);
#pragma unroll
    for (int c = 0; c < SEG4; ++c) {
      f16x4 va = ra[c];
#pragma unroll
      for (int l = 0; l < 4; ++l) {
        float av = (float)va[l];
        int j = 4 * c + l;
        sm[j] += av;
        sq[j] += av * av;
        mn[j] = fminf(mn[j], av);
        mx[j] = fmaxf(mx[j], av);
      }
    }
  }
  float iv = invd[n];
  bool has = (e1 > e0);
  _Float16* dst = agg + (size_t)n * (4 * F) + g * SEG;
#pragma unroll
  for (int c = 0; c < SEG4; ++c) {
    f16x4 vme, vmn, vmx, vsd;
#pragma unroll
    for (int l = 0; l < 4; ++l) {
      int j = 4 * c + l;
      float mean = sm[j] * iv;
      float var = sq[j] * iv - mean * mean;
      float sd = sqrtf(fmaxf(var, 0.f) + 1e-5f);
      vme[l] = (_Float16)mean;
      vmn[l] = has ? (_Float16)mn[j] : (_Float16)0.f;
      vmx[l] = has ? (_Float16)mx[j] : (_Float16)0.f;
      vsd[l] = (_Float16)sd;
    }
    *(f16x4*)(dst + 0 * F + 4 * c) = vme;
    *(f16x4*)(dst + 1 * F + 4 * c) = vmn;
    *(f16x4*)(dst + 2 * F + 4 * c) = vmx;
    *(f16x4*)(dst + 3 * F + 4 * c) = vsd;
  }
}

// ---------------- Phase B standalone: dense 13F GEMM (fp16 MFMA) ----------------
#define MFMA16(a, b, c) __builtin_amdgcn_mfma_f32_16x16x32_f16(a, b, c, 0, 0, 0)

template <int F, int FO, int FOP, bool RELU, typename OT>
__launch_bounds__(256)
__global__ void k_mlp(const _Float16* __restrict__ hin, const _Float16* __restrict__ agg,
                      const float* __restrict__ s1g, const float* __restrict__ s2g,
                      const _Float16* __restrict__ Wt, const float* __restrict__ bias,
                      OT* __restrict__ hout) {
  constexpr int K13 = 13 * F;
  constexpr int AGW = 4 * F + 8;   // row stride in halves; (4F+8)*2 bytes, 16B multiple
  constexpr int XW = F + 8;
  constexpr int NT = FOP / 16;
  constexpr int PPW = (2 * NT) / 4;
  __shared__ __align__(16) _Float16 s_agg[32][AGW];
  __shared__ __align__(16) _Float16 s_x[32][XW];
  __shared__ __align__(16) _Float16 s_wt[3][FOP][40];

  const int tid = threadIdx.x;
  const int n0 = blockIdx.x * 32;

  // stage self + agg tiles (coalesced f16x8)
  for (int idx = tid; idx < 32 * (F / 8); idx += 256) {
    int r = idx / (F / 8), c = idx % (F / 8);
    *(f16x8*)&s_x[r][8 * c] = *(const f16x8*)&hin[(size_t)(n0 + r) * F + 8 * c];
  }
  for (int idx = tid; idx < 32 * (4 * F / 8); idx += 256) {
    int r = idx / (4 * F / 8), c = idx % (4 * F / 8);
    *(f16x8*)&s_agg[r][8 * c] = *(const f16x8*)&agg[(size_t)(n0 + r) * (4 * F) + 8 * c];
  }
  __syncthreads();

  const int w = tid >> 6, ln = tid & 63;
  const int lm = ln & 15, q = ln >> 4;
  const int mt = w & 1;
  const int arow = mt * 16 + lm;
  f32x4 acc0[PPW], acc1[PPW], acc2[PPW];
#pragma unroll
  for (int i = 0; i < PPW; ++i)
#pragma unroll
    for (int t = 0; t < 4; ++t) { acc0[i][t] = 0.f; acc1[i][t] = 0.f; acc2[i][t] = 0.f; }

  // x segment (W rows [0, F))
  for (int k0 = 0; k0 < F; k0 += 32) {
    for (int u = tid; u < FOP * 4; u += 256) {
      int nn = u >> 2, qq = u & 3;
      *(f16x8*)&s_wt[0][nn][8 * qq] = *(const f16x8*)&Wt[(size_t)nn * K13 + k0 + 8 * qq];
    }
    __syncthreads();
    f16x8 a = *(const f16x8*)&s_x[arow][k0 + 8 * q];
#pragma unroll
    for (int i = 0; i < PPW; ++i) {
      int nt = (w >> 1) + 2 * i;
      f16x8 b = *(const f16x8*)&s_wt[0][nt * 16 + lm][8 * q];
      acc0[i] = MFMA16(a, b, acc0[i]);
    }
    __syncthreads();
  }
  // agg segments (W rows [F,5F),[5F,9F),[9F,13F)); shared A-frag, 3 acc sets
  for (int k0 = 0; k0 < 4 * F; k0 += 32) {
#pragma unroll
    for (int seg = 0; seg < 3; ++seg) {
      const _Float16* src = Wt + F + seg * 4 * F + k0;
      for (int u = tid; u < FOP * 4; u += 256) {
        int nn = u >> 2, qq = u & 3;
        *(f16x8*)&s_wt[seg][nn][8 * qq] = *(const f16x8*)&src[(size_t)nn * K13 + 8 * qq];
      }
    }
    __syncthreads();
    f16x8 a = *(const f16x8*)&s_agg[arow][k0 + 8 * q];
#pragma unroll
    for (int i = 0; i < PPW; ++i) {
      int nt = (w >> 1) + 2 * i;
      const int wrow = nt * 16 + lm;
      f16x8 b0 = *(const f16x8*)&s_wt[0][wrow][8 * q];
      acc0[i] = MFMA16(a, b0, acc0[i]);
      f16x8 b1 = *(const f16x8*)&s_wt[1][wrow][8 * q];
      acc1[i] = MFMA16(a, b1, acc1[i]);
      f16x8 b2 = *(const f16x8*)&s_wt[2][wrow][8 * q];
      acc2[i] = MFMA16(a, b2, acc2[i]);
    }
    __syncthreads();
  }

  // epilogue: D row = (lane>>4)*4 + t, col = lane&15
  float s1r[4], s2r[4];
#pragma unroll
  for (int t = 0; t < 4; ++t) {
    int node = n0 + mt * 16 + q * 4 + t;
    s1r[t] = s1g[node];
    s2r[t] = s2g[node];
  }
#pragma unroll
  for (int i = 0; i < PPW; ++i) {
    int nt = (w >> 1) + 2 * i;
    int ncol = nt * 16 + lm;
    if (FOP == FO || ncol < FO) {
      float bs = bias[ncol];
#pragma unroll
      for (int t = 0; t < 4; ++t) {
        int node = n0 + mt * 16 + q * 4 + t;
        float v = acc0[i][t] + s1r[t] * acc1[i][t] + s2r[t] * acc2[i][t] + bs;
        if (RELU) v = fmaxf(v, 0.f);
        hout[(size_t)node * FO + ncol] = (OT)v;
      }
    }
  }
}

// ---------------- BN stats / apply ----------------
template <typename T>
__global__ void k_colstats(const T* __restrict__ h, int n, int fo,
                           float* __restrict__ csum, float* __restrict__ csq) {
  __shared__ float ssum[96], ssq[96];
  int tid = threadIdx.x;
  if (tid < fo) { ssum[tid] = 0.f; ssq[tid] = 0.f; }
  __syncthreads();
  int total = n * fo;
  int T2 = gridDim.x * 256;
  int i = blockIdx.x * 256 + tid;
  int c = i % fo;
  int step = T2 % fo;
  for (; i < total; i += T2) {
    float v = (float)h[i];
    atomicAdd(&ssum[c], v);
    atomicAdd(&ssq[c], v * v);
    c += step;
    if (c >= fo) c -= fo;
  }
  __syncthreads();
  if (tid < fo) {
    atomicAdd(&csum[tid], ssum[tid]);
    atomicAdd(&csq[tid], ssq[tid]);
  }
}

template <typename T>
__global__ void k_bn(T* __restrict__ h, const float* __restrict__ csum,
                     const float* __restrict__ csq, const float* __restrict__ gg,
                     const float* __restrict__ be, int n, int fo, int relu) {
  int i = blockIdx.x * 256 + threadIdx.x;
  if (i >= n * fo) return;
  int c = i % fo;
  float invn = 1.f / (float)n;
  float mu = csum[c] * invn;
  float var = csq[c] * invn - mu * mu;
  float rs = rsqrtf(var + 1e-5f);
  float v = ((float)h[i] - mu) * rs * gg[c] + be[c];
  if (relu) v = fmaxf(v, 0.f);
  h[i] = (T)v;
}

// ---------------- pooling + head ----------------
__global__ void k_pool(const float* __restrict__ h, const int* __restrict__ batch,
                       float* __restrict__ zsum, float* __restrict__ gcnt, int n) {
  __shared__ float sv[NGRAPH * 20];
  __shared__ float sc[NGRAPH];
  int tid = threadIdx.x;
  for (int u = tid; u < NGRAPH * 20; u += 256) sv[u] = 0.f;
  if (tid < NGRAPH) sc[tid] = 0.f;
  __syncthreads();
  int i = blockIdx.x * 256 + tid;
  if (i < n) {
    int g = batch[i];
    atomicAdd(&sc[g], 1.f);
    for (int j = 0; j < 20; ++j) atomicAdd(&sv[g * 20 + j], h[(size_t)i * 20 + j]);
  }
  __syncthreads();
  if (tid < NGRAPH && sc[tid] != 0.f) {
    atomicAdd(&gcnt[tid], sc[tid]);
    for (int j = 0; j < 20; ++j) atomicAdd(&zsum[tid * 20 + j], sv[tid * 20 + j]);
  }
}

__global__ void k_head(const float* __restrict__ zsum, const float* __restrict__ gcnt,
                       const float* __restrict__ wl, const float* __restrict__ bl,
                       float* __restrict__ out) {
  int g = threadIdx.x;
  if (g >= NGRAPH) return;
  float z[20];
  float icg = 1.f / fmaxf(gcnt[g], 1.f);
#pragma unroll
  for (int j = 0; j < 20; ++j) {
    z[j] = zsum[g * 20 + j] * icg;
    out[NGRAPH * 11 + g * 20 + j] = z[j];  // second output: z
  }
  float lo[11];
#pragma unroll
  for (int o = 0; o < 11; ++o) {
    float a = bl[o];
    for (int j = 0; j < 20; ++j) a += z[j] * wl[j * 11 + o];
    lo[o] = a;
  }
  float m = lo[0];
  for (int o = 1; o < 11; ++o) m = fmaxf(m, lo[o]);
  float s = 0.f;
  for (int o = 0; o < 11; ++o) { lo[o] = expf(lo[o] - m); s += lo[o]; }
  float is = 1.f / s;
  for (int o = 0; o < 11; ++o) out[g * 11 + o] = lo[o] * is;  // first output: softmax
}

// ---------------- launch ----------------
static inline char* carve(char*& p, size_t bytes) {
  char* r = p;
  p += (bytes + 255) & ~(size_t)255;
  return r;
}

extern "C" void kernel_launch(void* const* d_in, const int* in_sizes, int n_in,
                              void* d_out, int out_size, void* d_ws, size_t ws_size,
                              hipStream_t stream) {
  const float* x = (const float*)d_in[0];
  const int* ei = (const int*)d_in[1];
  const int* batch = (const int*)d_in[2];
  const float* W0 = (const float*)d_in[3];
  const float* b0 = (const float*)d_in[4];
  const float* W1 = (const float*)d_in[5];
  const float* b1 = (const float*)d_in[6];
  const float* W2 = (const float*)d_in[7];
  const float* b2 = (const float*)d_in[8];
  const float* W3 = (const float*)d_in[9];
  const float* b3 = (const float*)d_in[10];
  const float* g0 = (const float*)d_in[11];
  const float* be0 = (const float*)d_in[12];
  const float* g1 = (const float*)d_in[13];
  const float* be1 = (const float*)d_in[14];
  const float* g2 = (const float*)d_in[15];
  const float* be2 = (const float*)d_in[16];
  const float* wl = (const float*)d_in[17];
  const float* bl = (const float*)d_in[18];
  float* out = (float*)d_out;

  const int E = in_sizes[1] / 2;       // 3200000
  const int NB = (NN + 255) / 256;     // 391

  char* p = (char*)d_ws;
  int* cnt = (int*)carve(p, (size_t)NN * 4);
  int* row_ptr = (int*)carve(p, (size_t)(NN + 1) * 4);
  int* cursor = (int*)carve(p, (size_t)NN * 4);
  int* bsum = (int*)carve(p, 2048);
  int* boff = (int*)carve(p, 2048);
  int* colv = (int*)carve(p, (size_t)E * 4);
  float* invd = (float*)carve(p, (size_t)NN * 4);
  float* s1v = (float*)carve(p, (size_t)NN * 4);
  float* s2v = (float*)carve(p, (size_t)NN * 4);
  _Float16* Wt0 = (_Float16*)carve(p, (size_t)96 * 832 * 2);
  _Float16* Wt1 = (_Float16*)carve(p, (size_t)64 * 1248 * 2);
  _Float16* Wt2 = (_Float16*)carve(p, (size_t)32 * 832 * 2);
  _Float16* Wt3 = (_Float16*)carve(p, (size_t)32 * 416 * 2);
  float* cs = (float*)carve(p, 192 * 4);
  float* csum = cs;
  float* csq = cs + 96;
  float* pacc = (float*)carve(p, (NGRAPH * 20 + NGRAPH) * 4);
  float* zsum = pacc;
  float* gcnt = pacc + NGRAPH * 20;
  _Float16* x16 = (_Float16*)carve(p, (size_t)NN * 64 * 2);
  _Float16* hA16 = (_Float16*)carve(p, (size_t)NN * 96 * 2);
  _Float16* hB16 = (_Float16*)carve(p, (size_t)NN * 96 * 2);
  _Float16* aggb = (_Float16*)carve(p, (size_t)NN * 4 * 96 * 2);  // max 4F = 384
  float* h3 = (float*)x16;  // reuse: x16 dead after L0 (h3 = 8MB < 12.8MB)

  // CSR + per-node scalars
  hipMemsetAsync(cnt, 0, (size_t)NN * 4, stream);
  hipMemsetAsync(pacc, 0, (NGRAPH * 20 + NGRAPH) * 4, stream);
  k_degree<<<(E + 255) / 256, 256, 0, stream>>>(ei, cnt, E);
  k_blocksum<<<NB, 256, 0, stream>>>(cnt, bsum, NN);
  k_scanb<<<1, 512, 0, stream>>>(bsum, boff, NB);
  k_scatter<<<NB, 256, 0, stream>>>(cnt, boff, row_ptr, NN, E);
  k_nodesc<<<NB, 256, 0, stream>>>(cnt, row_ptr, cursor, invd, s1v, s2v, NN);
  k_fillp<<<NPART * 256, 256, 0, stream>>>(ei, cursor, colv, E);

  // fp16 transposed weights + fp16 x
  k_wtprep<<<(96 * 832 + 255) / 256, 256, 0, stream>>>(W0, Wt0, 832, 96, 96);
  k_wtprep<<<(64 * 1248 + 255) / 256, 256, 0, stream>>>(W1, Wt1, 1248, 64, 64);
  k_wtprep<<<(32 * 832 + 255) / 256, 256, 0, stream>>>(W2, Wt2, 832, 32, 32);
  k_wtprep<<<(32 * 416 + 255) / 256, 256, 0, stream>>>(W3, Wt3, 416, 20, 32);
  k_xconv<<<(NN * 64 + 255) / 256, 256, 0, stream>>>(x, x16, NN * 64);

  const int GP = NN / 32;  // 3125

  // Layer 0: (64 -> 96), BN + ReLU
  k_agg<64, 6><<<GP, 256, 0, stream>>>(x16, row_ptr, colv, invd, aggb);
  k_mlp<64, 96, 96, false, _Float16><<<GP, 256, 0, stream>>>(x16, aggb, s1v, s2v, Wt0, b0, hA16);
  hipMemsetAsync(cs, 0, 192 * 4, stream);
  k_colstats<_Float16><<<512, 256, 0, stream>>>(hA16, NN, 96, csum, csq);
  k_bn<_Float16><<<(NN * 96 + 255) / 256, 256, 0, stream>>>(hA16, csum, csq, g0, be0, NN, 96, 1);

  // Layer 1: (96 -> 64), BN + ReLU
  k_agg<96, 4><<<GP, 256, 0, stream>>>(hA16, row_ptr, colv, invd, aggb);
  k_mlp<96, 64, 64, false, _Float16><<<GP, 256, 0, stream>>>(hA16, aggb, s1v, s2v, Wt1, b1, hB16);
  hipMemsetAsync(cs, 0, 192 * 4, stream);
  k_colstats<_Float16><<<512, 256, 0, stream>>>(hB16, NN, 64, csum, csq);
  k_bn<_Float16><<<(NN * 64 + 255) / 256, 256, 0, stream>>>(hB16, csum, csq, g1, be1, NN, 64, 1);

  // Layer 2: (64 -> 32), ReLU fused
  k_agg<64, 6><<<GP, 256, 0, stream>>>(hB16, row_ptr, colv, invd, aggb);
  k_mlp<64, 32, 32, true, _Float16><<<GP, 256, 0, stream>>>(hB16, aggb, s1v, s2v, Wt2, b2, hA16);

  // Layer 3: (32 -> 20), BN (no ReLU), fp32 out
  k_agg<32, 8><<<GP, 256, 0, stream>>>(hA16, row_ptr, colv, invd, aggb);
  k_mlp<32, 20, 32, false, float><<<GP, 256, 0, stream>>>(hA16, aggb, s1v, s2v, Wt3, b3, h3);
  hipMemsetAsync(cs, 0, 192 * 4, stream);
  k_colstats<float><<<512, 256, 0, stream>>>(h3, NN, 20, csum, csq);
  k_bn<float><<<(NN * 20 + 255) / 256, 256, 0, stream>>>(h3, csum, csq, g2, be2, NN, 20, 0);

  // global mean pool + linear + softmax
  k_pool<<<NB, 256, 0, stream>>>(h3, batch, zsum, gcnt, NN);
  k_head<<<1, 64, 0, stream>>>(zsum, gcnt, wl, bl, out);
}

// Round 6
// 1078.346 us; speedup vs baseline: 1.3226x; 1.0469x over previous
//
#include <hip/hip_runtime.h>

#define NN 100000
#define NGRAPH 64
#define NPART 8
#define AVGLOG 3.4965075614664802f

using f32x4 = __attribute__((ext_vector_type(4))) float;
using f16x8 = __attribute__((ext_vector_type(8))) _Float16;
using f16x4 = __attribute__((ext_vector_type(4))) _Float16;

// ---------------- CSR build ----------------
__global__ void k_degree(const int* __restrict__ ei, int* __restrict__ cnt, int E) {
  int e = blockIdx.x * 256 + threadIdx.x;
  if (e < E) atomicAdd(&cnt[__builtin_nontemporal_load(&ei[E + e])], 1);
}

__global__ void k_blocksum(const int* __restrict__ cnt, int* __restrict__ bsum, int n) {
  __shared__ int s[256];
  int i = blockIdx.x * 256 + threadIdx.x;
  s[threadIdx.x] = (i < n) ? cnt[i] : 0;
  __syncthreads();
  for (int off = 128; off > 0; off >>= 1) {
    if (threadIdx.x < off) s[threadIdx.x] += s[threadIdx.x + off];
    __syncthreads();
  }
  if (threadIdx.x == 0) bsum[blockIdx.x] = s[0];
}

__global__ void k_scanb(const int* __restrict__ bsum, int* __restrict__ boff, int nb) {
  __shared__ int s[512];
  int t = threadIdx.x;
  int v = (t < nb) ? bsum[t] : 0;
  s[t] = v;
  __syncthreads();
  for (int off = 1; off < 512; off <<= 1) {
    int u = (t >= off) ? s[t - off] : 0;
    __syncthreads();
    s[t] += u;
    __syncthreads();
  }
  if (t < nb) boff[t] = s[t] - v;  // exclusive block offsets
}

__global__ void k_scatter(const int* __restrict__ cnt, const int* __restrict__ boff,
                          int* __restrict__ row_ptr, int n, int etot) {
  __shared__ int s[256];
  int i = blockIdx.x * 256 + threadIdx.x;
  int v = (i < n) ? cnt[i] : 0;
  s[threadIdx.x] = v;
  __syncthreads();
  for (int off = 1; off < 256; off <<= 1) {
    int u = (threadIdx.x >= off) ? s[threadIdx.x - off] : 0;
    __syncthreads();
    s[threadIdx.x] += u;
    __syncthreads();
  }
  if (i < n) row_ptr[i] = boff[blockIdx.x] + s[threadIdx.x] - v;
  if (i == 0) row_ptr[n] = etot;
}

__global__ void k_nodesc(const int* __restrict__ cnt, const int* __restrict__ row_ptr,
                         int* __restrict__ cursor, float* __restrict__ invd,
                         float* __restrict__ s1v, float* __restrict__ s2v, int n) {
  int i = blockIdx.x * 256 + threadIdx.x;
  if (i >= n) return;
  cursor[i] = row_ptr[i];
  float degc = fmaxf((float)cnt[i], 1.f);
  invd[i] = 1.f / degc;
  float ld = logf(degc + 1.f);
  s1v[i] = ld * (1.f / AVGLOG);
  s2v[i] = AVGLOG / ld;
}

// Partitioned fill. nt loads keep the 25MB/partition ei stream OUT of L2 so the
// 1.6MB colv write window stays resident -> lines coalesce before eviction.
__global__ void k_fillp(const int* __restrict__ ei, int* __restrict__ cursor,
                        int* __restrict__ colv, int E) {
  const int part = blockIdx.x & (NPART - 1);
  const int lo = part * (NN / NPART), hi = lo + (NN / NPART);
  const int nch = gridDim.x >> 3;
  const int ch = blockIdx.x >> 3;
  const int stride = nch * 256;
  for (int e = ch * 256 + threadIdx.x; e < E; e += stride) {
    int d = __builtin_nontemporal_load(&ei[E + e]);
    if (d >= lo && d < hi) {
      int pos = atomicAdd(&cursor[d], 1);
      colv[pos] = __builtin_nontemporal_load(&ei[e]);
    }
  }
}

// W [K][FO] fp32 -> fp16 in MFMA B-fragment order:
// Wt[((kt*NT + nt)*64 + q*16+m)*8 + j] = W[k= kt*32+q*8+j][col= nt*16+m]
__global__ void k_wtprep(const float* __restrict__ W, _Float16* __restrict__ Wt,
                         int K, int FO, int FOP) {
  int i = blockIdx.x * 256 + threadIdx.x;
  if (i >= FOP * K) return;
  int nn = i / K, k = i - nn * K;
  float v = (nn < FO) ? W[k * FO + nn] : 0.f;
  int NT = FOP >> 4;
  int kt = k >> 5, q = (k >> 3) & 3, j = k & 7;
  int nt = nn >> 4, m = nn & 15;
  size_t idx = (((size_t)kt * NT + nt) * 64 + (q * 16 + m)) * 8 + j;
  Wt[idx] = (_Float16)v;
}

__global__ void k_xconv(const float* __restrict__ x, _Float16* __restrict__ x16, int n) {
  int i = blockIdx.x * 256 + threadIdx.x;
  if (i < n) x16[i] = (_Float16)x[i];
}

// ---------------- Phase A: gather/reduce; writes agg in MFMA A-frag order ----------------
// agg[((tile16*KTA + kt)*64 + q*16+m)*8 + j] = value(node=tile16*16+m, kk=kt*32+q*8+j)
template <int F, int WPE>
__launch_bounds__(256, WPE)
__global__ void k_agg(const _Float16* __restrict__ hin, const int* __restrict__ row_ptr,
                      const int* __restrict__ colv, const float* __restrict__ invd,
                      _Float16* __restrict__ agg) {
  const int tid = threadIdx.x;
  const int r = tid >> 3, g = tid & 7;
  const int n = blockIdx.x * 32 + r;
  const int e0 = row_ptr[n], e1 = row_ptr[n + 1];
  constexpr int SEG = F / 8;
  constexpr int SEG4 = SEG / 4;
  constexpr int KTA = F / 8;   // 4F/32
  float sm[SEG], sq[SEG], mn[SEG], mx[SEG];
  const float FINF = __builtin_inff();
#pragma unroll
  for (int j = 0; j < SEG; ++j) { sm[j] = 0.f; sq[j] = 0.f; mn[j] = FINF; mx[j] = -FINF; }
  int e = e0;
  for (; e + 1 < e1; e += 2) {
    int sA = colv[e], sB = colv[e + 1];
    const f16x4* ra = (const f16x4*)(hin + (size_t)sA * F + g * SEG);
    const f16x4* rb = (const f16x4*)(hin + (size_t)sB * F + g * SEG);
#pragma unroll
    for (int c = 0; c < SEG4; ++c) {
      f16x4 va = ra[c], vb = rb[c];
#pragma unroll
      for (int l = 0; l < 4; ++l) {
        float av = (float)va[l], bv = (float)vb[l];
        int j = 4 * c + l;
        sm[j] += av + bv;
        sq[j] += av * av + bv * bv;
        mn[j] = fminf(mn[j], fminf(av, bv));
        mx[j] = fmaxf(mx[j], fmaxf(av, bv));
      }
    }
  }
  if (e < e1) {
    int sA = colv[e];
    const f16x4* ra = (const f16x4*)(hin + (size_t)sA * F + g * SEG);
#pragma unroll
    for (int c = 0; c < SEG4; ++c) {
      f16x4 va = ra[c];
#pragma unroll
      for (int l = 0; l < 4; ++l) {
        float av = (float)va[l];
        int j = 4 * c + l;
        sm[j] += av;
        sq[j] += av * av;
        mn[j] = fminf(mn[j], av);
        mx[j] = fmaxf(mx[j], av);
      }
    }
  }
  float iv = invd[n];
  bool has = (e1 > e0);
  const int m = n & 15;
  const size_t tb = (size_t)(n >> 4) * KTA;
#pragma unroll
  for (int c = 0; c < SEG4; ++c) {
    f16x4 vals[4];
#pragma unroll
    for (int l = 0; l < 4; ++l) {
      int j = 4 * c + l;
      float mean = sm[j] * iv;
      float var = sq[j] * iv - mean * mean;
      float sd = sqrtf(fmaxf(var, 0.f) + 1e-5f);
      vals[0][l] = (_Float16)mean;
      vals[1][l] = has ? (_Float16)mn[j] : (_Float16)0.f;
      vals[2][l] = has ? (_Float16)mx[j] : (_Float16)0.f;
      vals[3][l] = (_Float16)sd;
    }
    int f0 = g * SEG + 4 * c;
#pragma unroll
    for (int a = 0; a < 4; ++a) {
      int kk0 = a * F + f0;
      int kt = kk0 >> 5, q = (kk0 >> 3) & 3, j0 = kk0 & 7;
      *(f16x4*)(agg + (tb + kt) * 512 + (q * 16 + m) * 8 + j0) = vals[a];
    }
  }
}

// ---------------- Phase B: global-direct MFMA GEMM (pre-swizzled operands) ----------------
#define MFMA16(a, b, c) __builtin_amdgcn_mfma_f32_16x16x32_f16(a, b, c, 0, 0, 0)

template <int F, int FO, int FOP, bool RELU, typename OT>
__launch_bounds__(256)
__global__ void k_mlp(const _Float16* __restrict__ hin, const _Float16* __restrict__ agg,
                      const float* __restrict__ s1g, const float* __restrict__ s2g,
                      const _Float16* __restrict__ Wt, const float* __restrict__ bias,
                      OT* __restrict__ hout) {
  constexpr int F32 = F / 32;
  constexpr int KTA = F / 8;
  constexpr int NT = FOP / 16;
  constexpr int PPW = (2 * NT) / 4;
  constexpr int XW = F + 8;
  __shared__ __align__(16) _Float16 s_x[32][XW];

  const int tid = threadIdx.x;
  const int n0 = blockIdx.x * 32;

  // stage self features once (coalesced f16x8), single barrier
  for (int idx = tid; idx < 32 * (F / 8); idx += 256) {
    int r = idx / (F / 8), c = idx % (F / 8);
    *(f16x8*)&s_x[r][8 * c] = *(const f16x8*)&hin[(size_t)(n0 + r) * F + 8 * c];
  }
  __syncthreads();

  const int w = tid >> 6, ln = tid & 63;
  const int lm = ln & 15, q = ln >> 4;
  const int mt = w & 1;
  const int arow = mt * 16 + lm;
  f32x4 acc0[PPW], acc1[PPW], acc2[PPW];
#pragma unroll
  for (int i = 0; i < PPW; ++i)
#pragma unroll
    for (int t = 0; t < 4; ++t) { acc0[i][t] = 0.f; acc1[i][t] = 0.f; acc2[i][t] = 0.f; }

  // x segment: A from LDS, B direct from global (L2-hot)
#pragma unroll
  for (int kt = 0; kt < F32; ++kt) {
    f16x8 a = *(const f16x8*)&s_x[arow][kt * 32 + 8 * q];
#pragma unroll
    for (int i = 0; i < PPW; ++i) {
      int nt = (w >> 1) + 2 * i;
      f16x8 b = *(const f16x8*)&Wt[(((size_t)kt * NT + nt) * 64 + ln) * 8];
      acc0[i] = MFMA16(a, b, acc0[i]);
    }
  }
  // agg segments: A direct from swizzled agg, one A-frag feeds 3 acc sets
  const size_t atb = (size_t)(blockIdx.x * 2 + mt) * KTA;
#pragma unroll
  for (int kt = 0; kt < KTA; ++kt) {
    f16x8 a = *(const f16x8*)&agg[(atb + kt) * 512 + ln * 8];
#pragma unroll
    for (int i = 0; i < PPW; ++i) {
      int nt = (w >> 1) + 2 * i;
      f16x8 b0 = *(const f16x8*)&Wt[(((size_t)(F32 + kt) * NT + nt) * 64 + ln) * 8];
      acc0[i] = MFMA16(a, b0, acc0[i]);
      f16x8 b1 = *(const f16x8*)&Wt[(((size_t)(F32 + KTA + kt) * NT + nt) * 64 + ln) * 8];
      acc1[i] = MFMA16(a, b1, acc1[i]);
      f16x8 b2 = *(const f16x8*)&Wt[(((size_t)(F32 + 2 * KTA + kt) * NT + nt) * 64 + ln) * 8];
      acc2[i] = MFMA16(a, b2, acc2[i]);
    }
  }

  // epilogue: D row = (lane>>4)*4 + t, col = lane&15
  float s1r[4], s2r[4];
#pragma unroll
  for (int t = 0; t < 4; ++t) {
    int node = n0 + mt * 16 + q * 4 + t;
    s1r[t] = s1g[node];
    s2r[t] = s2g[node];
  }
#pragma unroll
  for (int i = 0; i < PPW; ++i) {
    int nt = (w >> 1) + 2 * i;
    int ncol = nt * 16 + lm;
    if (FOP == FO || ncol < FO) {
      float bs = bias[ncol];
#pragma unroll
      for (int t = 0; t < 4; ++t) {
        int node = n0 + mt * 16 + q * 4 + t;
        float v = acc0[i][t] + s1r[t] * acc1[i][t] + s2r[t] * acc2[i][t] + bs;
        if (RELU) v = fmaxf(v, 0.f);
        hout[(size_t)node * FO + ncol] = (OT)v;
      }
    }
  }
}

// ---------------- BN stats / apply ----------------
template <typename T>
__global__ void k_colstats(const T* __restrict__ h, int n, int fo,
                           float* __restrict__ csum, float* __restrict__ csq) {
  __shared__ float ssum[96], ssq[96];
  int tid = threadIdx.x;
  if (tid < fo) { ssum[tid] = 0.f; ssq[tid] = 0.f; }
  __syncthreads();
  int total = n * fo;
  int T2 = gridDim.x * 256;
  int i = blockIdx.x * 256 + tid;
  int c = i % fo;
  int step = T2 % fo;
  for (; i < total; i += T2) {
    float v = (float)h[i];
    atomicAdd(&ssum[c], v);
    atomicAdd(&ssq[c], v * v);
    c += step;
    if (c >= fo) c -= fo;
  }
  __syncthreads();
  if (tid < fo) {
    atomicAdd(&csum[tid], ssum[tid]);
    atomicAdd(&csq[tid], ssq[tid]);
  }
}

template <typename T>
__global__ void k_bn(T* __restrict__ h, const float* __restrict__ csum,
                     const float* __restrict__ csq, const float* __restrict__ gg,
                     const float* __restrict__ be, int n, int fo, int relu) {
  int i = blockIdx.x * 256 + threadIdx.x;
  if (i >= n * fo) return;
  int c = i % fo;
  float invn = 1.f / (float)n;
  float mu = csum[c] * invn;
  float var = csq[c] * invn - mu * mu;
  float rs = rsqrtf(var + 1e-5f);
  float v = ((float)h[i] - mu) * rs * gg[c] + be[c];
  if (relu) v = fmaxf(v, 0.f);
  h[i] = (T)v;
}

// ---------------- pooling + head ----------------
__global__ void k_pool(const float* __restrict__ h, const int* __restrict__ batch,
                       float* __restrict__ zsum, float* __restrict__ gcnt, int n) {
  __shared__ float sv[NGRAPH * 20];
  __shared__ float sc[NGRAPH];
  int tid = threadIdx.x;
  for (int u = tid; u < NGRAPH * 20; u += 256) sv[u] = 0.f;
  if (tid < NGRAPH) sc[tid] = 0.f;
  __syncthreads();
  int i = blockIdx.x * 256 + tid;
  if (i < n) {
    int g = batch[i];
    atomicAdd(&sc[g], 1.f);
    for (int j = 0; j < 20; ++j) atomicAdd(&sv[g * 20 + j], h[(size_t)i * 20 + j]);
  }
  __syncthreads();
  if (tid < NGRAPH && sc[tid] != 0.f) {
    atomicAdd(&gcnt[tid], sc[tid]);
    for (int j = 0; j < 20; ++j) atomicAdd(&zsum[tid * 20 + j], sv[tid * 20 + j]);
  }
}

__global__ void k_head(const float* __restrict__ zsum, const float* __restrict__ gcnt,
                       const float* __restrict__ wl, const float* __restrict__ bl,
                       float* __restrict__ out) {
  int g = threadIdx.x;
  if (g >= NGRAPH) return;
  float z[20];
  float icg = 1.f / fmaxf(gcnt[g], 1.f);
#pragma unroll
  for (int j = 0; j < 20; ++j) {
    z[j] = zsum[g * 20 + j] * icg;
    out[NGRAPH * 11 + g * 20 + j] = z[j];  // second output: z
  }
  float lo[11];
#pragma unroll
  for (int o = 0; o < 11; ++o) {
    float a = bl[o];
    for (int j = 0; j < 20; ++j) a += z[j] * wl[j * 11 + o];
    lo[o] = a;
  }
  float m = lo[0];
  for (int o = 1; o < 11; ++o) m = fmaxf(m, lo[o]);
  float s = 0.f;
  for (int o = 0; o < 11; ++o) { lo[o] = expf(lo[o] - m); s += lo[o]; }
  float is = 1.f / s;
  for (int o = 0; o < 11; ++o) out[g * 11 + o] = lo[o] * is;  // first output: softmax
}

// ---------------- launch ----------------
static inline char* carve(char*& p, size_t bytes) {
  char* r = p;
  p += (bytes + 255) & ~(size_t)255;
  return r;
}

extern "C" void kernel_launch(void* const* d_in, const int* in_sizes, int n_in,
                              void* d_out, int out_size, void* d_ws, size_t ws_size,
                              hipStream_t stream) {
  const float* x = (const float*)d_in[0];
  const int* ei = (const int*)d_in[1];
  const int* batch = (const int*)d_in[2];
  const float* W0 = (const float*)d_in[3];
  const float* b0 = (const float*)d_in[4];
  const float* W1 = (const float*)d_in[5];
  const float* b1 = (const float*)d_in[6];
  const float* W2 = (const float*)d_in[7];
  const float* b2 = (const float*)d_in[8];
  const float* W3 = (const float*)d_in[9];
  const float* b3 = (const float*)d_in[10];
  const float* g0 = (const float*)d_in[11];
  const float* be0 = (const float*)d_in[12];
  const float* g1 = (const float*)d_in[13];
  const float* be1 = (const float*)d_in[14];
  const float* g2 = (const float*)d_in[15];
  const float* be2 = (const float*)d_in[16];
  const float* wl = (const float*)d_in[17];
  const float* bl = (const float*)d_in[18];
  float* out = (float*)d_out;

  const int E = in_sizes[1] / 2;       // 3200000
  const int NB = (NN + 255) / 256;     // 391

  char* p = (char*)d_ws;
  int* cnt = (int*)carve(p, (size_t)NN * 4);
  int* row_ptr = (int*)carve(p, (size_t)(NN + 1) * 4);
  int* cursor = (int*)carve(p, (size_t)NN * 4);
  int* bsum = (int*)carve(p, 2048);
  int* boff = (int*)carve(p, 2048);
  int* colv = (int*)carve(p, (size_t)E * 4);
  float* invd = (float*)carve(p, (size_t)NN * 4);
  float* s1v = (float*)carve(p, (size_t)NN * 4);
  float* s2v = (float*)carve(p, (size_t)NN * 4);
  _Float16* Wt0 = (_Float16*)carve(p, (size_t)96 * 832 * 2);
  _Float16* Wt1 = (_Float16*)carve(p, (size_t)64 * 1248 * 2);
  _Float16* Wt2 = (_Float16*)carve(p, (size_t)32 * 832 * 2);
  _Float16* Wt3 = (_Float16*)carve(p, (size_t)32 * 416 * 2);
  float* cs = (float*)carve(p, 192 * 4);
  float* csum = cs;
  float* csq = cs + 96;
  float* pacc = (float*)carve(p, (NGRAPH * 20 + NGRAPH) * 4);
  float* zsum = pacc;
  float* gcnt = pacc + NGRAPH * 20;
  _Float16* x16 = (_Float16*)carve(p, (size_t)NN * 64 * 2);
  _Float16* hA16 = (_Float16*)carve(p, (size_t)NN * 96 * 2);
  _Float16* hB16 = (_Float16*)carve(p, (size_t)NN * 96 * 2);
  _Float16* aggb = (_Float16*)carve(p, (size_t)NN * 4 * 96 * 2);  // swizzled, max 4F=384
  float* h3 = (float*)x16;  // reuse: x16 dead after L0 (8MB < 12.8MB)

  // CSR + per-node scalars
  hipMemsetAsync(cnt, 0, (size_t)NN * 4, stream);
  hipMemsetAsync(pacc, 0, (NGRAPH * 20 + NGRAPH) * 4, stream);
  k_degree<<<(E + 255) / 256, 256, 0, stream>>>(ei, cnt, E);
  k_blocksum<<<NB, 256, 0, stream>>>(cnt, bsum, NN);
  k_scanb<<<1, 512, 0, stream>>>(bsum, boff, NB);
  k_scatter<<<NB, 256, 0, stream>>>(cnt, boff, row_ptr, NN, E);
  k_nodesc<<<NB, 256, 0, stream>>>(cnt, row_ptr, cursor, invd, s1v, s2v, NN);
  k_fillp<<<NPART * 256, 256, 0, stream>>>(ei, cursor, colv, E);

  // fp16 swizzled weights + fp16 x
  k_wtprep<<<(96 * 832 + 255) / 256, 256, 0, stream>>>(W0, Wt0, 832, 96, 96);
  k_wtprep<<<(64 * 1248 + 255) / 256, 256, 0, stream>>>(W1, Wt1, 1248, 64, 64);
  k_wtprep<<<(32 * 832 + 255) / 256, 256, 0, stream>>>(W2, Wt2, 832, 32, 32);
  k_wtprep<<<(32 * 416 + 255) / 256, 256, 0, stream>>>(W3, Wt3, 416, 20, 32);
  k_xconv<<<(NN * 64 + 255) / 256, 256, 0, stream>>>(x, x16, NN * 64);

  const int GP = NN / 32;  // 3125

  // Layer 0: (64 -> 96), BN + ReLU
  k_agg<64, 6><<<GP, 256, 0, stream>>>(x16, row_ptr, colv, invd, aggb);
  k_mlp<64, 96, 96, false, _Float16><<<GP, 256, 0, stream>>>(x16, aggb, s1v, s2v, Wt0, b0, hA16);
  hipMemsetAsync(cs, 0, 192 * 4, stream);
  k_colstats<_Float16><<<512, 256, 0, stream>>>(hA16, NN, 96, csum, csq);
  k_bn<_Float16><<<(NN * 96 + 255) / 256, 256, 0, stream>>>(hA16, csum, csq, g0, be0, NN, 96, 1);

  // Layer 1: (96 -> 64), BN + ReLU
  k_agg<96, 4><<<GP, 256, 0, stream>>>(hA16, row_ptr, colv, invd, aggb);
  k_mlp<96, 64, 64, false, _Float16><<<GP, 256, 0, stream>>>(hA16, aggb, s1v, s2v, Wt1, b1, hB16);
  hipMemsetAsync(cs, 0, 192 * 4, stream);
  k_colstats<_Float16><<<512, 256, 0, stream>>>(hB16, NN, 64, csum, csq);
  k_bn<_Float16><<<(NN * 64 + 255) / 256, 256, 0, stream>>>(hB16, csum, csq, g1, be1, NN, 64, 1);

  // Layer 2: (64 -> 32), ReLU fused
  k_agg<64, 6><<<GP, 256, 0, stream>>>(hB16, row_ptr, colv, invd, aggb);
  k_mlp<64, 32, 32, true, _Float16><<<GP, 256, 0, stream>>>(hB16, aggb, s1v, s2v, Wt2, b2, hA16);

  // Layer 3: (32 -> 20), BN (no ReLU), fp32 out
  k_agg<32, 8><<<GP, 256, 0, stream>>>(hA16, row_ptr, colv, invd, aggb);
  k_mlp<32, 20, 32, false, float><<<GP, 256, 0, stream>>>(hA16, aggb, s1v, s2v, Wt3, b3, h3);
  hipMemsetAsync(cs, 0, 192 * 4, stream);
  k_colstats<float><<<512, 256, 0, stream>>>(h3, NN, 20, csum, csq);
  k_bn<float><<<(NN * 20 + 255) / 256, 256, 0, stream>>>(h3, csum, csq, g2, be2, NN, 20, 0);

  // global mean pool + linear + softmax
  k_pool<<<NB, 256, 0, stream>>>(h3, batch, zsum, gcnt, NN);
  k_head<<<1, 64, 0, stream>>>(zsum, gcnt, wl, bl, out);
}